// Round 11
// baseline (184.657 us; speedup 1.0000x reference)
//
#include <hip/hip_runtime.h>
#include <hip/hip_bf16.h>
#include <cmath>

constexpr int N_ = 2;
constexpr int L_ = 2048;
constexpr int H_ = 16;
constexpr int E_ = 1024;
constexpr int ROWS_ = N_ * L_ * H_;   // 65536 token-head rows
constexpr float KSCALE = 0.04508422002778010648f;   // log2(e)/32, folded into k

typedef __attribute__((ext_vector_type(8))) short bf16x8;
typedef __attribute__((ext_vector_type(4))) float f32x4;
typedef unsigned short ushort_t;
#define MFMA16(a, b, c) __builtin_amdgcn_mfma_f32_16x16x32_bf16(a, b, c, 0, 0, 0)

__device__ __forceinline__ unsigned short f2bf(float x) {
    union { float f; unsigned u; } v; v.f = x;
    return (unsigned short)((v.u + 0x7fffu + ((v.u >> 16) & 1u)) >> 16);   // RNE
}
// HW-packed bf16 pair (v_cvt_pk_bf16_f32 on gfx950)
__device__ __forceinline__ unsigned pack2(float a, float b) {
    __hip_bfloat162 t = __float22bfloat162_rn(make_float2(a, b));
    union { __hip_bfloat162 h; unsigned u; } v; v.h = t;
    return v.u;
}
// gfx950 register-pair lane swaps (quad permutation, preserves lane&15)
__device__ __forceinline__ void plswap32(unsigned &a, unsigned &b) {
    asm("v_permlane32_swap_b32 %0, %1" : "+v"(a), "+v"(b));
}
__device__ __forceinline__ void plswap16(unsigned &a, unsigned &b) {
    asm("v_permlane16_swap_b32 %0, %1" : "+v"(a), "+v"(b));
}

// ---------------------------------------------------------------------------
// Kernel 1: per-head projections, bf16 MFMA.
// 512 threads / 128 rows per block, shared weight staging (R10 structure).
// R11: amdgpu_waves_per_eu(4,4) — LDS (63 KB -> 2 blocks/CU) caps occupancy
// at 4 waves/EU anyway; without the max-bound the allocator was minimizing
// VGPRs toward an unreachable 8/EU target and spilling.
// conv_misc merged as tail blocks (>= 512).
// Emits q row-major [n][l][h][d]; k row-major PRE-SCALED by log2(e)/32;
// v TRANSPOSED [n][h][d][l].
// ---------------------------------------------------------------------------
__global__ __launch_bounds__(512)
__attribute__((amdgpu_waves_per_eu(4, 4)))
void proj_kernel(
    const float* __restrict__ keys, const float* __restrict__ queries,
    const float* __restrict__ Wk, const float* __restrict__ Wq, const float* __restrict__ Wv,
    ushort_t* __restrict__ qo, ushort_t* __restrict__ ko, ushort_t* __restrict__ vto,
    const float* __restrict__ Wo, const int* __restrict__ mask,
    ushort_t* __restrict__ Wob, float* __restrict__ maskf)
{
    constexpr int P = 72;
    __shared__ __align__(16) ushort_t Xq[128 * P];   // also reused as [64][136] V^T
    __shared__ __align__(16) ushort_t Xk[128 * P];
    __shared__ __align__(16) ushort_t Wqs[64 * P];
    __shared__ __align__(16) ushort_t Wks[64 * P];
    __shared__ __align__(16) ushort_t Wvs[64 * P];
    const int tid = threadIdx.x;

    if (blockIdx.x >= 512) {           // merged conv_misc tail (512 threads)
        const int b = blockIdx.x - 512;
        if (b < 512) {
            const int i = (b * 512 + tid) * 4;
            const float4 w = *(const float4*)&Wo[i];
            *(uint2*)&Wob[i] = make_uint2(pack2(w.x, w.y), pack2(w.z, w.w));
        } else {
            const int j = (b - 512) * 512 + tid;
            if (j < N_ * L_) maskf[j] = mask[j] ? 0.f : -1e9f;
        }
        return;
    }

    const int lt = blockIdx.x & 15;            // 16 tiles of 128 rows
    const int h  = (blockIdx.x >> 4) & 15;
    const int n  = blockIdx.x >> 8;
    const int r0 = tid >> 4, c4 = (tid & 15) * 4;   // r0: 0..31

    // stage X (128 rows) + 3 weights (64 rows each)
#pragma unroll
    for (int j = 0; j < 4; ++j) {
        const int r = r0 + 32 * j;
        const size_t xoff = (size_t)(n * L_ + lt * 128 + r) * E_ + h * 64 + c4;
        const float4 xq = *(const float4*)&queries[xoff];
        const float4 xk = *(const float4*)&keys[xoff];
        *(uint2*)&Xq[r * P + c4] = make_uint2(pack2(xq.x, xq.y), pack2(xq.z, xq.w));
        *(uint2*)&Xk[r * P + c4] = make_uint2(pack2(xk.x, xk.y), pack2(xk.z, xk.w));
    }
#pragma unroll
    for (int j = 0; j < 2; ++j) {
        const int r = r0 + 32 * j;
        const float4 wq = *(const float4*)&Wq[r * 64 + c4];
        const float4 wk = *(const float4*)&Wk[r * 64 + c4];
        const float4 wv = *(const float4*)&Wv[r * 64 + c4];
        *(uint2*)&Wqs[r * P + c4] = make_uint2(pack2(wq.x, wq.y), pack2(wq.z, wq.w));
        *(uint2*)&Wks[r * P + c4] = make_uint2(pack2(wk.x, wk.y), pack2(wk.z, wk.w));
        *(uint2*)&Wvs[r * P + c4] = make_uint2(pack2(wv.x, wv.y), pack2(wv.z, wv.w));
    }
    __syncthreads();

    const int wave = tid >> 6, lane = tid & 63;
    const int quad = lane >> 4, l16 = lane & 15;
    const int arow = (wave * 16 + l16) * P;       // wave owns rows wave*16..+15
    const f32x4 zero = (f32x4){0.f, 0.f, 0.f, 0.f};

    bf16x8 a0 = *(const bf16x8*)&Xq[arow + quad * 8];
    bf16x8 a1 = *(const bf16x8*)&Xq[arow + 32 + quad * 8];
    bf16x8 c0 = *(const bf16x8*)&Xk[arow + quad * 8];
    bf16x8 c1 = *(const bf16x8*)&Xk[arow + 32 + quad * 8];

    // phase 1: qf = X_q @ Wq^T, kf = X_k @ Wk^T
    f32x4 qf[4], kf[4];
#pragma unroll
    for (int nt = 0; nt < 4; ++nt) {
        const int brow = (nt * 16 + l16) * P;
        f32x4 acc = MFMA16(a0, *(const bf16x8*)&Wqs[brow + quad * 8], zero);
        qf[nt] = MFMA16(a1, *(const bf16x8*)&Wqs[brow + 32 + quad * 8], acc);
        acc = MFMA16(c0, *(const bf16x8*)&Wks[brow + quad * 8], zero);
        kf[nt] = MFMA16(c1, *(const bf16x8*)&Wks[brow + 32 + quad * 8], acc);
    }
    __syncthreads();   // all Xq/Xk input reads complete

    // write q (bf16) -> Xq rows, k*KSCALE -> Xk rows (wave-private stripes)
    const int crow = wave * 16 + quad * 4;
#pragma unroll
    for (int nt = 0; nt < 4; ++nt)
#pragma unroll
        for (int reg = 0; reg < 4; ++reg) {
            Xq[(crow + reg) * P + nt * 16 + l16] = f2bf(qf[nt][reg]);
            Xk[(crow + reg) * P + nt * 16 + l16] = f2bf(kf[nt][reg] * KSCALE);
        }
    asm volatile("s_waitcnt lgkmcnt(0)" ::: "memory");   // wave-private rows

    bf16x8 va0 = *(const bf16x8*)&Xq[arow + quad * 8];
    bf16x8 va1 = *(const bf16x8*)&Xq[arow + 32 + quad * 8];

    // phase 2: v = q @ Wv^T
    f32x4 vf[4];
#pragma unroll
    for (int nt = 0; nt < 4; ++nt) {
        const int brow = (nt * 16 + l16) * P;
        f32x4 acc = MFMA16(va0, *(const bf16x8*)&Wvs[brow + quad * 8], zero);
        vf[nt] = MFMA16(va1, *(const bf16x8*)&Wvs[brow + 32 + quad * 8], acc);
    }
    __syncthreads();   // all waves' q/k writes visible

    // store q, k (128 rows)
#pragma unroll
    for (int j = 0; j < 4; ++j) {
        const int r = r0 + 32 * j;
        const size_t qkoff = (size_t)(n * L_ + lt * 128 + r) * E_ + h * 64 + c4;
        *(uint2*)&qo[qkoff] = *(const uint2*)&Xq[r * P + c4];
        *(uint2*)&ko[qkoff] = *(const uint2*)&Xk[r * P + c4];
    }
    __syncthreads();   // Xq reads done before V^T overwrite

    // write v TRANSPOSED into Xq reinterpreted as [64 d][136] (272B rows: 16B-aligned)
#pragma unroll
    for (int nt = 0; nt < 4; ++nt)
#pragma unroll
        for (int reg = 0; reg < 4; ++reg)
            Xq[(nt * 16 + l16) * 136 + crow + reg] = f2bf(vf[nt][reg]);
    __syncthreads();

    // store vt: 64 d-rows x 128 l-cols
#pragma unroll
    for (int j = 0; j < 2; ++j) {
        const int r = (tid >> 4) + 32 * j;        // 0..63
        const int cc = (tid & 15) * 8;            // 0..120
        const size_t vtoff = ((size_t)(n * H_ + h) * 64 + r) * L_ + lt * 128 + cc;
        *(uint4*)&vto[vtoff] = *(const uint4*)&Xq[r * 136 + cc];
    }
}

// ---------------------------------------------------------------------------
// Kernel 2: MFMA flash attention, KEY-SPLIT (R3 structure).
// R11: amdgpu_waves_per_eu(4,4). LDS (72 KB -> 2 blocks/CU) caps occupancy
// at exactly 4 waves/EU; without a max-bound the allocator pinned VGPRs at
// 64 (8/EU target) against a ~140-reg live set -> permanent scratch spill
// (FETCH +9 MB, WRITE +19.6 MB every round since R3). Now 128 VGPRs/wave.
// mask double-buffer (mfn) dropped -> JIT mf load (16 KB L2-resident, R6-
// proven harmless) so the peak live set fits under 128.
// 512 threads = 8 waves = 4 q-groups (32 q-rows, 2 strips) x 2 key-groups.
// Double-buffered 128-key pair-tiles, ONE barrier. P in-register permlane
// transpose. lacc scalar + shfl reduce.
// XCD swizzle: each XCD serves 4 heads (K/V set 2 MB < 4 MB L2).
// ---------------------------------------------------------------------------
__global__ __launch_bounds__(512)
__attribute__((amdgpu_waves_per_eu(4, 4)))
void attn_kernel(
    const ushort_t* __restrict__ q, const ushort_t* __restrict__ k,
    const ushort_t* __restrict__ vt, const float* __restrict__ maskf,
    ushort_t* __restrict__ attn)
{
    constexpr int PK = 72;     // Kp row pad (ushorts): 128 keys x 64 d
    constexpr int PV = 136;    // Vp row pad (ushorts): 64 d x 128 keys
    constexpr int KP_SZ = 128 * PK;   // 9216 ushorts per buffer
    constexpr int VP_SZ = 64 * PV;    // 8704 ushorts per buffer
    __shared__ __align__(16) unsigned char SMEM[(2 * KP_SZ + 2 * VP_SZ) * 2 + 512];
    ushort_t* Kp = (ushort_t*)SMEM;                          // [2][128*72]
    ushort_t* Vp = (ushort_t*)(SMEM + 2 * KP_SZ * 2);        // [2][64*136]
    float*    Ls = (float*)(SMEM + (2 * KP_SZ + 2 * VP_SZ) * 2);  // [128]
    float*    Oc = (float*)SMEM;                             // combine [64][132] (reuse)
    float*    Lp = (float*)(SMEM + 2 * KP_SZ * 2);           // combine lacc [128] (reuse)

    // XCD-aware decode: xcd = g&7 gets heads [4*xcd, 4*xcd+4)
    const int g = blockIdx.x;
    const int xcd = g & 7, j0 = g >> 3;
    const int nh = xcd * 4 + (j0 & 3);
    const int qt = j0 >> 2;                // 0..15 (tiles of 128 rows)
    const int n = nh >> 4, h = nh & 15;

    const int tid = threadIdx.x;
    const int wave = tid >> 6, lane = tid & 63;
    const int l16 = lane & 15, quad = lane >> 4;
    const int qg = wave & 3, kg = wave >> 2;
    const int r8 = tid >> 3, c8 = (tid & 7) * 8;     // K staging: 64 rows x 16B (x2)
    const int vr8 = tid >> 4, vc8 = (tid & 15) * 8;  // V staging: 32 rows x 16B (x2)

    const ushort_t* kh = k  + (size_t)n * L_ * E_ + h * 64;      // + key*E_ + d
    const ushort_t* vh = vt + (size_t)(n * H_ + h) * 64 * L_;    // + d*L_ + key
    const float*    mh = maskf + n * L_;
    const size_t qrow0 = (size_t)n * L_ + qt * 128 + qg * 32;

    // hoisted Q B-frags [strip][chain] (t-invariant); wave owns 32 q-rows
    bf16x8 qb[2][2];
#pragma unroll
    for (int st = 0; st < 2; ++st)
#pragma unroll
        for (int c = 0; c < 2; ++c)
            qb[st][c] = *(const bf16x8*)&q[(qrow0 + st * 16 + l16) * E_ + h * 64 + c * 32 + quad * 8];

    // pair-tile 0 staging prefetch
    uint4 kr[2], vr[2];
#pragma unroll
    for (int j = 0; j < 2; ++j) {
        kr[j] = *(const uint4*)&kh[(size_t)(64 * j + r8) * E_ + c8];
        vr[j] = *(const uint4*)&vh[(size_t)(vr8 + 32 * j) * L_ + vc8];
    }

    // commit pair-tile 0 into buffer 0
#pragma unroll
    for (int j = 0; j < 2; ++j) {
        *(uint4*)&Kp[(64 * j + r8) * PK + c8]  = kr[j];
        *(uint4*)&Vp[(vr8 + 32 * j) * PV + vc8] = vr[j];
    }
    __syncthreads();

    float lacc[2] = {0.f, 0.f};
    f32x4 O[2][4];
#pragma unroll
    for (int st = 0; st < 2; ++st)
#pragma unroll
        for (int dt = 0; dt < 4; ++dt) O[st][dt] = (f32x4){0.f, 0.f, 0.f, 0.f};

    for (int s = 0; s < 16; ++s) {
        const int cur = s & 1, nxt = cur ^ 1;
        const int sn = (s < 15) ? s + 1 : 15;

        // mask C-init for THIS superstep, JIT (16 KB L2-resident; saves 16
        // persistent VGPRs vs double-buffer; latency hides under kA ds_reads)
        f32x4 mf[4];
#pragma unroll
        for (int mk = 0; mk < 4; ++mk)
            mf[mk] = *(const f32x4*)&mh[128 * s + kg * 64 + mk * 16 + quad * 4];

        // issue global prefetch for superstep s+1 (lands in regs during compute)
#pragma unroll
        for (int j = 0; j < 2; ++j) {
            kr[j] = *(const uint4*)&kh[(size_t)(128 * sn + 64 * j + r8) * E_ + c8];
            vr[j] = *(const uint4*)&vh[(size_t)(vr8 + 32 * j) * L_ + 128 * sn + vc8];
        }

        // K A-frags for THIS kg's 64-key half
        bf16x8 kA[4][2];
#pragma unroll
        for (int mk = 0; mk < 4; ++mk)
#pragma unroll
            for (int c = 0; c < 2; ++c)
                kA[mk][c] = *(const bf16x8*)&Kp[cur * KP_SZ + (kg * 64 + mk * 16 + l16) * PK + c * 32 + quad * 8];

        // S^T = K'*Q^T + mask_init : C[key=16mk+quad*4+reg][q=l16]
        f32x4 sA[2][4];
#pragma unroll
        for (int st = 0; st < 2; ++st)
#pragma unroll
            for (int mk = 0; mk < 4; ++mk) {
                f32x4 acc = mf[mk];
                acc = MFMA16(kA[mk][0], qb[st][0], acc);
                sA[st][mk] = MFMA16(kA[mk][1], qb[st][1], acc);
            }

        // V B-frags for THIS kg's key half (issued before softmax VALU chain)
        bf16x8 vB[4][2];
#pragma unroll
        for (int dt = 0; dt < 4; ++dt)
#pragma unroll
            for (int c = 0; c < 2; ++c)
                vB[dt][c] = *(const bf16x8*)&Vp[cur * VP_SZ + (dt * 16 + l16) * PV + kg * 64 + c * 32 + quad * 8];

        // p = exp2(s); pack + in-register quad permutation (permlane swaps):
        // consumer lane (quad,l16) word w of chain c = keys c*32+8*quad+2w..+1
        // of P-row l16 = PV A-frag layout. (l16 preserved by both swaps.)
        bf16x8 pa[2][2];
#pragma unroll
        for (int st = 0; st < 2; ++st) {
            unsigned u[4][2];
#pragma unroll
            for (int mk = 0; mk < 4; ++mk) {
                const float p0 = __builtin_amdgcn_exp2f(sA[st][mk][0]);
                const float p1 = __builtin_amdgcn_exp2f(sA[st][mk][1]);
                const float p2 = __builtin_amdgcn_exp2f(sA[st][mk][2]);
                const float p3 = __builtin_amdgcn_exp2f(sA[st][mk][3]);
                lacc[st] += (p0 + p1) + (p2 + p3);
                u[mk][0] = pack2(p0, p1);
                u[mk][1] = pack2(p2, p3);
            }
#pragma unroll
            for (int c = 0; c < 2; ++c) {
                union { unsigned w[4]; bf16x8 v; } pw;
#pragma unroll
                for (int hh = 0; hh < 2; ++hh) {
                    unsigned a = u[2 * c][hh], b = u[2 * c + 1][hh];
                    plswap32(a, b);
                    plswap16(a, b);
                    pw.w[hh] = a; pw.w[2 + hh] = b;
                }
                pa[st][c] = pw.v;
            }
        }

        // O += P*V (partial over this kg's keys)
#pragma unroll
        for (int st = 0; st < 2; ++st)
#pragma unroll
            for (int dt = 0; dt < 4; ++dt) {
                O[st][dt] = MFMA16(pa[st][0], vB[dt][0], O[st][dt]);
                O[st][dt] = MFMA16(pa[st][1], vB[dt][1], O[st][dt]);
            }

        // commit s+1 into the idle buffer; ONE barrier covers reads(cur)+writes(nxt)
#pragma unroll
        for (int j = 0; j < 2; ++j) {
            *(uint4*)&Kp[nxt * KP_SZ + (64 * j + r8) * PK + c8]   = kr[j];
            *(uint4*)&Vp[nxt * VP_SZ + (vr8 + 32 * j) * PV + vc8] = vr[j];
        }
        __syncthreads();
    }

    // --- combine the two key-group partials (they simply add: no max-shift) ---
    float vsum[2];
#pragma unroll
    for (int st = 0; st < 2; ++st) {
        float v = lacc[st];
        v += __shfl_xor(v, 16);
        v += __shfl_xor(v, 32);
        vsum[st] = v;
    }

    if (kg == 1) {
        // publish partial O (layout Oc[d][row], b128-contiguous) + partial l
#pragma unroll
        for (int st = 0; st < 2; ++st) {
            if (quad == 0) Lp[qg * 32 + st * 16 + l16] = vsum[st];
#pragma unroll
            for (int dt = 0; dt < 4; ++dt)
                *(f32x4*)&Oc[(dt * 16 + l16) * 132 + qg * 32 + st * 16 + quad * 4] = O[st][dt];
        }
    }
    __syncthreads();

    if (kg == 0) {
#pragma unroll
        for (int st = 0; st < 2; ++st) {
#pragma unroll
            for (int dt = 0; dt < 4; ++dt) {
                const f32x4 op = *(const f32x4*)&Oc[(dt * 16 + l16) * 132 + qg * 32 + st * 16 + quad * 4];
                O[st][dt] += op;
            }
            const float vtot = vsum[st] + Lp[qg * 32 + st * 16 + l16];
            if (quad == 0) Ls[qg * 32 + st * 16 + l16] = 1.f / vtot;
        }
        asm volatile("s_waitcnt lgkmcnt(0)" ::: "memory");   // wave-private Ls
        f32x4 linv[2];
#pragma unroll
        for (int st = 0; st < 2; ++st)
            linv[st] = *(const f32x4*)&Ls[qg * 32 + st * 16 + quad * 4];

#pragma unroll
        for (int st = 0; st < 2; ++st)
#pragma unroll
            for (int dt = 0; dt < 4; ++dt)
#pragma unroll
                for (int reg = 0; reg < 4; ++reg) {
                    const size_t row = qrow0 + st * 16 + quad * 4 + reg;
                    attn[row * E_ + h * 64 + dt * 16 + l16] = f2bf(O[st][dt][reg] * linv[st][reg]);
                }
    }
}

// ---------------------------------------------------------------------------
// Kernel 4: out = attn(4096x1024) @ Wo^T + bo.
// 64x64 tiles, 1024 blocks = 4 blocks/CU (R8-measured best). LDS 18.4 KB
// allows up to 8 blocks/CU, so the compiler's low-VGPR/high-occupancy
// preference is correct here — no waves_per_eu clamp.
// ---------------------------------------------------------------------------
__global__ __launch_bounds__(256) void outproj_kernel(
    const ushort_t* __restrict__ attn, const ushort_t* __restrict__ Wob,
    const float* __restrict__ bo, float* __restrict__ out)
{
    constexpr int P = 72;
    __shared__ __align__(16) ushort_t As[64 * P];
    __shared__ __align__(16) ushort_t Bs[64 * P];
    const int tid = threadIdx.x;
    const int bc = (blockIdx.x & 15) * 64;
    const int br = (blockIdx.x >> 4) * 64;
    const int r0 = tid >> 4, c4 = (tid & 15) * 4;
    const int wave = tid >> 6, lane = tid & 63;
    const int quad = lane >> 4, l16 = lane & 15;

    uint2 ar[4], brg[4];
#pragma unroll
    for (int j = 0; j < 4; ++j) {
        ar[j]  = *(const uint2*)&attn[(size_t)(br + r0 + 16 * j) * E_ + c4];
        brg[j] = *(const uint2*)&Wob[(size_t)(bc + r0 + 16 * j) * E_ + c4];
    }

    f32x4 acc[4];
#pragma unroll
    for (int nt = 0; nt < 4; ++nt) acc[nt] = (f32x4){0.f, 0.f, 0.f, 0.f};

    for (int kt = 0; kt < 16; ++kt) {
#pragma unroll
        for (int j = 0; j < 4; ++j) {
            *(uint2*)&As[(r0 + 16 * j) * P + c4] = ar[j];
            *(uint2*)&Bs[(r0 + 16 * j) * P + c4] = brg[j];
        }
        __syncthreads();
        const int knext = ((kt < 15) ? (kt + 1) : kt) * 64;
#pragma unroll
        for (int j = 0; j < 4; ++j) {
            ar[j]  = *(const uint2*)&attn[(size_t)(br + r0 + 16 * j) * E_ + knext + c4];
            brg[j] = *(const uint2*)&Wob[(size_t)(bc + r0 + 16 * j) * E_ + knext + c4];
        }

        bf16x8 aw[2], bw[4][2];
#pragma unroll
        for (int c = 0; c < 2; ++c)
            aw[c] = *(const bf16x8*)&As[(wave * 16 + l16) * P + c * 32 + quad * 8];
#pragma unroll
        for (int nt = 0; nt < 4; ++nt)
#pragma unroll
            for (int c = 0; c < 2; ++c)
                bw[nt][c] = *(const bf16x8*)&Bs[(nt * 16 + l16) * P + c * 32 + quad * 8];
#pragma unroll
        for (int nt = 0; nt < 4; ++nt) {
            acc[nt] = MFMA16(aw[0], bw[nt][0], acc[nt]);
            acc[nt] = MFMA16(aw[1], bw[nt][1], acc[nt]);
        }
        __syncthreads();
    }
#pragma unroll
    for (int nt = 0; nt < 4; ++nt) {
        const float bias = bo[bc + nt * 16 + l16];
#pragma unroll
        for (int reg = 0; reg < 4; ++reg)
            out[(size_t)(br + wave * 16 + quad * 4 + reg) * E_ + bc + nt * 16 + l16] =
                acc[nt][reg] + bias;
    }
}

// ---------------------------------------------------------------------------
extern "C" void kernel_launch(void* const* d_in, const int* in_sizes, int n_in,
                              void* d_out, int out_size, void* d_ws, size_t ws_size,
                              hipStream_t stream)
{
    const float* keys    = (const float*)d_in[0];
    const float* queries = (const float*)d_in[1];
    // d_in[2] (values) is UNUSED by the reference: v = q @ Wv.T
    const int*   mask    = (const int*)d_in[3];
    const float* Wk      = (const float*)d_in[4];
    const float* Wq      = (const float*)d_in[5];
    const float* Wv      = (const float*)d_in[6];
    const float* Wo      = (const float*)d_in[7];
    const float* bo      = (const float*)d_in[8];
    float* out = (float*)d_out;

    // workspace (bf16): q, k, vT, attn = 8 MB each; Wo_bf 2 MB; maskf 16 KB
    ushort_t* qbf  = (ushort_t*)d_ws;
    ushort_t* kbf  = qbf + (size_t)ROWS_ * 64;
    ushort_t* vtbf = kbf + (size_t)ROWS_ * 64;
    ushort_t* abf  = vtbf + (size_t)ROWS_ * 64;
    ushort_t* wob  = abf + (size_t)ROWS_ * 64;
    float*    mskf = (float*)(wob + (size_t)E_ * E_);

    // proj grid: 512 proj blocks (128 rows each) + 512 Wo-conv + 8 mask blocks
    proj_kernel<<<512 + 512 + 8, 512, 0, stream>>>(
        keys, queries, Wk, Wq, Wv, qbf, kbf, vtbf, Wo, mask, wob, mskf);
    attn_kernel<<<N_ * H_ * (L_ / 128), 512, 0, stream>>>(qbf, kbf, vtbf, mskf, abf);
    outproj_kernel<<<(N_ * L_ / 64) * (E_ / 64), 256, 0, stream>>>(abf, wob, bo, out);
}

// Round 12
// 177.705 us; speedup vs baseline: 1.0391x; 1.0391x over previous
//
#include <hip/hip_runtime.h>
#include <hip/hip_bf16.h>
#include <cmath>

constexpr int N_ = 2;
constexpr int L_ = 2048;
constexpr int H_ = 16;
constexpr int E_ = 1024;
constexpr int ROWS_ = N_ * L_ * H_;   // 65536 token-head rows
constexpr float KSCALE = 0.04508422002778010648f;   // log2(e)/32, folded into k

typedef __attribute__((ext_vector_type(8))) short bf16x8;
typedef __attribute__((ext_vector_type(4))) float f32x4;
typedef unsigned short ushort_t;
#define MFMA16(a, b, c) __builtin_amdgcn_mfma_f32_16x16x32_bf16(a, b, c, 0, 0, 0)

__device__ __forceinline__ unsigned short f2bf(float x) {
    union { float f; unsigned u; } v; v.f = x;
    return (unsigned short)((v.u + 0x7fffu + ((v.u >> 16) & 1u)) >> 16);   // RNE
}
// HW-packed bf16 pair (v_cvt_pk_bf16_f32 on gfx950)
__device__ __forceinline__ unsigned pack2(float a, float b) {
    __hip_bfloat162 t = __float22bfloat162_rn(make_float2(a, b));
    union { __hip_bfloat162 h; unsigned u; } v; v.h = t;
    return v.u;
}
// gfx950 register-pair lane swaps (quad permutation, preserves lane&15)
__device__ __forceinline__ void plswap32(unsigned &a, unsigned &b) {
    asm("v_permlane32_swap_b32 %0, %1" : "+v"(a), "+v"(b));
}
__device__ __forceinline__ void plswap16(unsigned &a, unsigned &b) {
    asm("v_permlane16_swap_b32 %0, %1" : "+v"(a), "+v"(b));
}

// ---------------------------------------------------------------------------
// Kernel 1: per-head projections, bf16 MFMA.
// R10-measured best: 512 threads / 128 rows per block, shared weight
// staging, LDS 63 KB -> 2 blocks/CU = 4 waves/EU.
// conv_misc merged as tail blocks (>= 512).
// NOTE (R11 lesson): on gfx950 the unified VGPR/AGPR file means the
// reported VGPR_Count=64 + ~64 acc regs is ALREADY the full 128/4-wave
// budget — waves_per_eu(4,4) was a no-op and is not used.
// Emits q row-major [n][l][h][d]; k row-major PRE-SCALED by log2(e)/32;
// v TRANSPOSED [n][h][d][l].
// ---------------------------------------------------------------------------
__global__ __launch_bounds__(512, 4) void proj_kernel(
    const float* __restrict__ keys, const float* __restrict__ queries,
    const float* __restrict__ Wk, const float* __restrict__ Wq, const float* __restrict__ Wv,
    ushort_t* __restrict__ qo, ushort_t* __restrict__ ko, ushort_t* __restrict__ vto,
    const float* __restrict__ Wo, const int* __restrict__ mask,
    ushort_t* __restrict__ Wob, float* __restrict__ maskf)
{
    constexpr int P = 72;
    __shared__ __align__(16) ushort_t Xq[128 * P];   // also reused as [64][136] V^T
    __shared__ __align__(16) ushort_t Xk[128 * P];
    __shared__ __align__(16) ushort_t Wqs[64 * P];
    __shared__ __align__(16) ushort_t Wks[64 * P];
    __shared__ __align__(16) ushort_t Wvs[64 * P];
    const int tid = threadIdx.x;

    if (blockIdx.x >= 512) {           // merged conv_misc tail (512 threads)
        const int b = blockIdx.x - 512;
        if (b < 512) {
            const int i = (b * 512 + tid) * 4;
            const float4 w = *(const float4*)&Wo[i];
            *(uint2*)&Wob[i] = make_uint2(pack2(w.x, w.y), pack2(w.z, w.w));
        } else {
            const int j = (b - 512) * 512 + tid;
            if (j < N_ * L_) maskf[j] = mask[j] ? 0.f : -1e9f;
        }
        return;
    }

    const int lt = blockIdx.x & 15;            // 16 tiles of 128 rows
    const int h  = (blockIdx.x >> 4) & 15;
    const int n  = blockIdx.x >> 8;
    const int r0 = tid >> 4, c4 = (tid & 15) * 4;   // r0: 0..31

    // stage X (128 rows) + 3 weights (64 rows each)
#pragma unroll
    for (int j = 0; j < 4; ++j) {
        const int r = r0 + 32 * j;
        const size_t xoff = (size_t)(n * L_ + lt * 128 + r) * E_ + h * 64 + c4;
        const float4 xq = *(const float4*)&queries[xoff];
        const float4 xk = *(const float4*)&keys[xoff];
        *(uint2*)&Xq[r * P + c4] = make_uint2(pack2(xq.x, xq.y), pack2(xq.z, xq.w));
        *(uint2*)&Xk[r * P + c4] = make_uint2(pack2(xk.x, xk.y), pack2(xk.z, xk.w));
    }
#pragma unroll
    for (int j = 0; j < 2; ++j) {
        const int r = r0 + 32 * j;
        const float4 wq = *(const float4*)&Wq[r * 64 + c4];
        const float4 wk = *(const float4*)&Wk[r * 64 + c4];
        const float4 wv = *(const float4*)&Wv[r * 64 + c4];
        *(uint2*)&Wqs[r * P + c4] = make_uint2(pack2(wq.x, wq.y), pack2(wq.z, wq.w));
        *(uint2*)&Wks[r * P + c4] = make_uint2(pack2(wk.x, wk.y), pack2(wk.z, wk.w));
        *(uint2*)&Wvs[r * P + c4] = make_uint2(pack2(wv.x, wv.y), pack2(wv.z, wv.w));
    }
    __syncthreads();

    const int wave = tid >> 6, lane = tid & 63;
    const int quad = lane >> 4, l16 = lane & 15;
    const int arow = (wave * 16 + l16) * P;       // wave owns rows wave*16..+15
    const f32x4 zero = (f32x4){0.f, 0.f, 0.f, 0.f};

    bf16x8 a0 = *(const bf16x8*)&Xq[arow + quad * 8];
    bf16x8 a1 = *(const bf16x8*)&Xq[arow + 32 + quad * 8];
    bf16x8 c0 = *(const bf16x8*)&Xk[arow + quad * 8];
    bf16x8 c1 = *(const bf16x8*)&Xk[arow + 32 + quad * 8];

    // phase 1: qf = X_q @ Wq^T, kf = X_k @ Wk^T
    f32x4 qf[4], kf[4];
#pragma unroll
    for (int nt = 0; nt < 4; ++nt) {
        const int brow = (nt * 16 + l16) * P;
        f32x4 acc = MFMA16(a0, *(const bf16x8*)&Wqs[brow + quad * 8], zero);
        qf[nt] = MFMA16(a1, *(const bf16x8*)&Wqs[brow + 32 + quad * 8], acc);
        acc = MFMA16(c0, *(const bf16x8*)&Wks[brow + quad * 8], zero);
        kf[nt] = MFMA16(c1, *(const bf16x8*)&Wks[brow + 32 + quad * 8], acc);
    }
    __syncthreads();   // all Xq/Xk input reads complete

    // write q (bf16) -> Xq rows, k*KSCALE -> Xk rows (wave-private stripes)
    const int crow = wave * 16 + quad * 4;
#pragma unroll
    for (int nt = 0; nt < 4; ++nt)
#pragma unroll
        for (int reg = 0; reg < 4; ++reg) {
            Xq[(crow + reg) * P + nt * 16 + l16] = f2bf(qf[nt][reg]);
            Xk[(crow + reg) * P + nt * 16 + l16] = f2bf(kf[nt][reg] * KSCALE);
        }
    asm volatile("s_waitcnt lgkmcnt(0)" ::: "memory");   // wave-private rows

    bf16x8 va0 = *(const bf16x8*)&Xq[arow + quad * 8];
    bf16x8 va1 = *(const bf16x8*)&Xq[arow + 32 + quad * 8];

    // phase 2: v = q @ Wv^T
    f32x4 vf[4];
#pragma unroll
    for (int nt = 0; nt < 4; ++nt) {
        const int brow = (nt * 16 + l16) * P;
        f32x4 acc = MFMA16(va0, *(const bf16x8*)&Wvs[brow + quad * 8], zero);
        vf[nt] = MFMA16(va1, *(const bf16x8*)&Wvs[brow + 32 + quad * 8], acc);
    }
    __syncthreads();   // all waves' q/k writes visible

    // store q, k (128 rows)
#pragma unroll
    for (int j = 0; j < 4; ++j) {
        const int r = r0 + 32 * j;
        const size_t qkoff = (size_t)(n * L_ + lt * 128 + r) * E_ + h * 64 + c4;
        *(uint2*)&qo[qkoff] = *(const uint2*)&Xq[r * P + c4];
        *(uint2*)&ko[qkoff] = *(const uint2*)&Xk[r * P + c4];
    }
    __syncthreads();   // Xq reads done before V^T overwrite

    // write v TRANSPOSED into Xq reinterpreted as [64 d][136] (272B rows: 16B-aligned)
#pragma unroll
    for (int nt = 0; nt < 4; ++nt)
#pragma unroll
        for (int reg = 0; reg < 4; ++reg)
            Xq[(nt * 16 + l16) * 136 + crow + reg] = f2bf(vf[nt][reg]);
    __syncthreads();

    // store vt: 64 d-rows x 128 l-cols
#pragma unroll
    for (int j = 0; j < 2; ++j) {
        const int r = (tid >> 4) + 32 * j;        // 0..63
        const int cc = (tid & 15) * 8;            // 0..120
        const size_t vtoff = ((size_t)(n * H_ + h) * 64 + r) * L_ + lt * 128 + cc;
        *(uint4*)&vto[vtoff] = *(const uint4*)&Xq[r * 136 + cc];
    }
}

// ---------------------------------------------------------------------------
// Kernel 2: MFMA flash attention, KEY-SPLIT (R3/R10-measured best ~61 us).
// 512 threads = 8 waves = 4 q-groups (32 q-rows, 2 strips) x 2 key-groups.
// Double-buffered 128-key pair-tiles, ONE barrier. P in-register permlane
// transpose. lacc scalar + shfl reduce. mf prefetched (mfn) — R11 proved
// the JIT variant costs ~6 us (dependent L2 load on QK critical path).
// XCD swizzle: each XCD serves 4 heads (K/V set 2 MB < 4 MB L2).
// ---------------------------------------------------------------------------
__global__ __launch_bounds__(512, 4) void attn_kernel(
    const ushort_t* __restrict__ q, const ushort_t* __restrict__ k,
    const ushort_t* __restrict__ vt, const float* __restrict__ maskf,
    ushort_t* __restrict__ attn)
{
    constexpr int PK = 72;     // Kp row pad (ushorts): 128 keys x 64 d
    constexpr int PV = 136;    // Vp row pad (ushorts): 64 d x 128 keys
    constexpr int KP_SZ = 128 * PK;   // 9216 ushorts per buffer
    constexpr int VP_SZ = 64 * PV;    // 8704 ushorts per buffer
    __shared__ __align__(16) unsigned char SMEM[(2 * KP_SZ + 2 * VP_SZ) * 2 + 512];
    ushort_t* Kp = (ushort_t*)SMEM;                          // [2][128*72]
    ushort_t* Vp = (ushort_t*)(SMEM + 2 * KP_SZ * 2);        // [2][64*136]
    float*    Ls = (float*)(SMEM + (2 * KP_SZ + 2 * VP_SZ) * 2);  // [128]
    float*    Oc = (float*)SMEM;                             // combine [64][132] (reuse)
    float*    Lp = (float*)(SMEM + 2 * KP_SZ * 2);           // combine lacc [128] (reuse)

    // XCD-aware decode: xcd = g&7 gets heads [4*xcd, 4*xcd+4)
    const int g = blockIdx.x;
    const int xcd = g & 7, j0 = g >> 3;
    const int nh = xcd * 4 + (j0 & 3);
    const int qt = j0 >> 2;                // 0..15 (tiles of 128 rows)
    const int n = nh >> 4, h = nh & 15;

    const int tid = threadIdx.x;
    const int wave = tid >> 6, lane = tid & 63;
    const int l16 = lane & 15, quad = lane >> 4;
    const int qg = wave & 3, kg = wave >> 2;
    const int r8 = tid >> 3, c8 = (tid & 7) * 8;     // K staging: 64 rows x 16B (x2)
    const int vr8 = tid >> 4, vc8 = (tid & 15) * 8;  // V staging: 32 rows x 16B (x2)

    const ushort_t* kh = k  + (size_t)n * L_ * E_ + h * 64;      // + key*E_ + d
    const ushort_t* vh = vt + (size_t)(n * H_ + h) * 64 * L_;    // + d*L_ + key
    const float*    mh = maskf + n * L_;
    const size_t qrow0 = (size_t)n * L_ + qt * 128 + qg * 32;

    // hoisted Q B-frags [strip][chain] (t-invariant); wave owns 32 q-rows
    bf16x8 qb[2][2];
#pragma unroll
    for (int st = 0; st < 2; ++st)
#pragma unroll
        for (int c = 0; c < 2; ++c)
            qb[st][c] = *(const bf16x8*)&q[(qrow0 + st * 16 + l16) * E_ + h * 64 + c * 32 + quad * 8];

    // pair-tile 0 staging prefetch + this kg's mask C-init prefetch
    uint4 kr[2], vr[2];
#pragma unroll
    for (int j = 0; j < 2; ++j) {
        kr[j] = *(const uint4*)&kh[(size_t)(64 * j + r8) * E_ + c8];
        vr[j] = *(const uint4*)&vh[(size_t)(vr8 + 32 * j) * L_ + vc8];
    }
    f32x4 mf[4];
#pragma unroll
    for (int mk = 0; mk < 4; ++mk) mf[mk] = *(const f32x4*)&mh[kg * 64 + mk * 16 + quad * 4];

    // commit pair-tile 0 into buffer 0
#pragma unroll
    for (int j = 0; j < 2; ++j) {
        *(uint4*)&Kp[(64 * j + r8) * PK + c8]  = kr[j];
        *(uint4*)&Vp[(vr8 + 32 * j) * PV + vc8] = vr[j];
    }
    __syncthreads();

    float lacc[2] = {0.f, 0.f};
    f32x4 O[2][4];
#pragma unroll
    for (int st = 0; st < 2; ++st)
#pragma unroll
        for (int dt = 0; dt < 4; ++dt) O[st][dt] = (f32x4){0.f, 0.f, 0.f, 0.f};

    for (int s = 0; s < 16; ++s) {
        const int cur = s & 1, nxt = cur ^ 1;
        const int sn = (s < 15) ? s + 1 : 15;

        // issue global prefetch for superstep s+1 (lands in regs during compute)
#pragma unroll
        for (int j = 0; j < 2; ++j) {
            kr[j] = *(const uint4*)&kh[(size_t)(128 * sn + 64 * j + r8) * E_ + c8];
            vr[j] = *(const uint4*)&vh[(size_t)(vr8 + 32 * j) * L_ + 128 * sn + vc8];
        }
        f32x4 mfn[4];
#pragma unroll
        for (int mk = 0; mk < 4; ++mk)
            mfn[mk] = *(const f32x4*)&mh[128 * sn + kg * 64 + mk * 16 + quad * 4];

        // K A-frags for THIS kg's 64-key half
        bf16x8 kA[4][2];
#pragma unroll
        for (int mk = 0; mk < 4; ++mk)
#pragma unroll
            for (int c = 0; c < 2; ++c)
                kA[mk][c] = *(const bf16x8*)&Kp[cur * KP_SZ + (kg * 64 + mk * 16 + l16) * PK + c * 32 + quad * 8];

        // S^T = K'*Q^T + mask_init : C[key=16mk+quad*4+reg][q=l16]
        f32x4 sA[2][4];
#pragma unroll
        for (int st = 0; st < 2; ++st)
#pragma unroll
            for (int mk = 0; mk < 4; ++mk) {
                f32x4 acc = mf[mk];
                acc = MFMA16(kA[mk][0], qb[st][0], acc);
                sA[st][mk] = MFMA16(kA[mk][1], qb[st][1], acc);
            }

        // V B-frags for THIS kg's key half (issued before softmax VALU chain)
        bf16x8 vB[4][2];
#pragma unroll
        for (int dt = 0; dt < 4; ++dt)
#pragma unroll
            for (int c = 0; c < 2; ++c)
                vB[dt][c] = *(const bf16x8*)&Vp[cur * VP_SZ + (dt * 16 + l16) * PV + kg * 64 + c * 32 + quad * 8];

        // p = exp2(s); pack + in-register quad permutation (permlane swaps):
        // consumer lane (quad,l16) word w of chain c = keys c*32+8*quad+2w..+1
        // of P-row l16 = PV A-frag layout. (l16 preserved by both swaps.)
        bf16x8 pa[2][2];
#pragma unroll
        for (int st = 0; st < 2; ++st) {
            unsigned u[4][2];
#pragma unroll
            for (int mk = 0; mk < 4; ++mk) {
                const float p0 = __builtin_amdgcn_exp2f(sA[st][mk][0]);
                const float p1 = __builtin_amdgcn_exp2f(sA[st][mk][1]);
                const float p2 = __builtin_amdgcn_exp2f(sA[st][mk][2]);
                const float p3 = __builtin_amdgcn_exp2f(sA[st][mk][3]);
                lacc[st] += (p0 + p1) + (p2 + p3);
                u[mk][0] = pack2(p0, p1);
                u[mk][1] = pack2(p2, p3);
            }
#pragma unroll
            for (int c = 0; c < 2; ++c) {
                union { unsigned w[4]; bf16x8 v; } pw;
#pragma unroll
                for (int hh = 0; hh < 2; ++hh) {
                    unsigned a = u[2 * c][hh], b = u[2 * c + 1][hh];
                    plswap32(a, b);
                    plswap16(a, b);
                    pw.w[hh] = a; pw.w[2 + hh] = b;
                }
                pa[st][c] = pw.v;
            }
        }

        // O += P*V (partial over this kg's keys)
#pragma unroll
        for (int st = 0; st < 2; ++st)
#pragma unroll
            for (int dt = 0; dt < 4; ++dt) {
                O[st][dt] = MFMA16(pa[st][0], vB[dt][0], O[st][dt]);
                O[st][dt] = MFMA16(pa[st][1], vB[dt][1], O[st][dt]);
            }

        // commit s+1 into the idle buffer; ONE barrier covers reads(cur)+writes(nxt)
#pragma unroll
        for (int j = 0; j < 2; ++j) {
            *(uint4*)&Kp[nxt * KP_SZ + (64 * j + r8) * PK + c8]   = kr[j];
            *(uint4*)&Vp[nxt * VP_SZ + (vr8 + 32 * j) * PV + vc8] = vr[j];
        }
#pragma unroll
        for (int mk = 0; mk < 4; ++mk) mf[mk] = mfn[mk];
        __syncthreads();
    }

    // --- combine the two key-group partials (they simply add: no max-shift) ---
    float vsum[2];
#pragma unroll
    for (int st = 0; st < 2; ++st) {
        float v = lacc[st];
        v += __shfl_xor(v, 16);
        v += __shfl_xor(v, 32);
        vsum[st] = v;
    }

    if (kg == 1) {
        // publish partial O (layout Oc[d][row], b128-contiguous) + partial l
#pragma unroll
        for (int st = 0; st < 2; ++st) {
            if (quad == 0) Lp[qg * 32 + st * 16 + l16] = vsum[st];
#pragma unroll
            for (int dt = 0; dt < 4; ++dt)
                *(f32x4*)&Oc[(dt * 16 + l16) * 132 + qg * 32 + st * 16 + quad * 4] = O[st][dt];
        }
    }
    __syncthreads();

    if (kg == 0) {
#pragma unroll
        for (int st = 0; st < 2; ++st) {
#pragma unroll
            for (int dt = 0; dt < 4; ++dt) {
                const f32x4 op = *(const f32x4*)&Oc[(dt * 16 + l16) * 132 + qg * 32 + st * 16 + quad * 4];
                O[st][dt] += op;
            }
            const float vtot = vsum[st] + Lp[qg * 32 + st * 16 + l16];
            if (quad == 0) Ls[qg * 32 + st * 16 + l16] = 1.f / vtot;
        }
        asm volatile("s_waitcnt lgkmcnt(0)" ::: "memory");   // wave-private Ls
        f32x4 linv[2];
#pragma unroll
        for (int st = 0; st < 2; ++st)
            linv[st] = *(const f32x4*)&Ls[qg * 32 + st * 16 + quad * 4];

#pragma unroll
        for (int st = 0; st < 2; ++st)
#pragma unroll
            for (int dt = 0; dt < 4; ++dt)
#pragma unroll
                for (int reg = 0; reg < 4; ++reg) {
                    const size_t row = qrow0 + st * 16 + quad * 4 + reg;
                    attn[row * E_ + h * 64 + dt * 16 + l16] = f2bf(O[st][dt][reg] * linv[st][reg]);
                }
    }
}

// ---------------------------------------------------------------------------
// Kernel 4: out = attn(4096x1024) @ Wo^T + bo.
// 64x64 tiles, 1024 blocks = 4 blocks/CU (R8-measured best).
// R12: bijective XCD swizzle (grid 1024 = 8 x 128): each XCD gets 128
// consecutive work-ids = 8 br-groups x all 16 bc -> its L2 holds 8 A-panels
// (1 MB) + whole Wob (2 MB) < 4 MB, instead of every XCD fetching every
// A-panel (T1, +10% on HBM-bound tiled ops, m192).
// ---------------------------------------------------------------------------
__global__ __launch_bounds__(256) void outproj_kernel(
    const ushort_t* __restrict__ attn, const ushort_t* __restrict__ Wob,
    const float* __restrict__ bo, float* __restrict__ out)
{
    constexpr int P = 72;
    __shared__ __align__(16) ushort_t As[64 * P];
    __shared__ __align__(16) ushort_t Bs[64 * P];
    const int tid = threadIdx.x;
    // bijective XCD swizzle: wg = (bid&7)*128 + (bid>>3)
    const int wg = (blockIdx.x & 7) * 128 + (blockIdx.x >> 3);
    const int bc = (wg & 15) * 64;
    const int br = (wg >> 4) * 64;
    const int r0 = tid >> 4, c4 = (tid & 15) * 4;
    const int wave = tid >> 6, lane = tid & 63;
    const int quad = lane >> 4, l16 = lane & 15;

    uint2 ar[4], brg[4];
#pragma unroll
    for (int j = 0; j < 4; ++j) {
        ar[j]  = *(const uint2*)&attn[(size_t)(br + r0 + 16 * j) * E_ + c4];
        brg[j] = *(const uint2*)&Wob[(size_t)(bc + r0 + 16 * j) * E_ + c4];
    }

    f32x4 acc[4];
#pragma unroll
    for (int nt = 0; nt < 4; ++nt) acc[nt] = (f32x4){0.f, 0.f, 0.f, 0.f};

    for (int kt = 0; kt < 16; ++kt) {
#pragma unroll
        for (int j = 0; j < 4; ++j) {
            *(uint2*)&As[(r0 + 16 * j) * P + c4] = ar[j];
            *(uint2*)&Bs[(r0 + 16 * j) * P + c4] = brg[j];
        }
        __syncthreads();
        const int knext = ((kt < 15) ? (kt + 1) : kt) * 64;
#pragma unroll
        for (int j = 0; j < 4; ++j) {
            ar[j]  = *(const uint2*)&attn[(size_t)(br + r0 + 16 * j) * E_ + knext + c4];
            brg[j] = *(const uint2*)&Wob[(size_t)(bc + r0 + 16 * j) * E_ + knext + c4];
        }

        bf16x8 aw[2], bw[4][2];
#pragma unroll
        for (int c = 0; c < 2; ++c)
            aw[c] = *(const bf16x8*)&As[(wave * 16 + l16) * P + c * 32 + quad * 8];
#pragma unroll
        for (int nt = 0; nt < 4; ++nt)
#pragma unroll
            for (int c = 0; c < 2; ++c)
                bw[nt][c] = *(const bf16x8*)&Bs[(nt * 16 + l16) * P + c * 32 + quad * 8];
#pragma unroll
        for (int nt = 0; nt < 4; ++nt) {
            acc[nt] = MFMA16(aw[0], bw[nt][0], acc[nt]);
            acc[nt] = MFMA16(aw[1], bw[nt][1], acc[nt]);
        }
        __syncthreads();
    }
#pragma unroll
    for (int nt = 0; nt < 4; ++nt) {
        const float bias = bo[bc + nt * 16 + l16];
#pragma unroll
        for (int reg = 0; reg < 4; ++reg)
            out[(size_t)(br + wave * 16 + quad * 4 + reg) * E_ + bc + nt * 16 + l16] =
                acc[nt][reg] + bias;
    }
}

// ---------------------------------------------------------------------------
extern "C" void kernel_launch(void* const* d_in, const int* in_sizes, int n_in,
                              void* d_out, int out_size, void* d_ws, size_t ws_size,
                              hipStream_t stream)
{
    const float* keys    = (const float*)d_in[0];
    const float* queries = (const float*)d_in[1];
    // d_in[2] (values) is UNUSED by the reference: v = q @ Wv.T
    const int*   mask    = (const int*)d_in[3];
    const float* Wk      = (const float*)d_in[4];
    const float* Wq      = (const float*)d_in[5];
    const float* Wv      = (const float*)d_in[6];
    const float* Wo      = (const float*)d_in[7];
    const float* bo      = (const float*)d_in[8];
    float* out = (float*)d_out;

    // workspace (bf16): q, k, vT, attn = 8 MB each; Wo_bf 2 MB; maskf 16 KB
    ushort_t* qbf  = (ushort_t*)d_ws;
    ushort_t* kbf  = qbf + (size_t)ROWS_ * 64;
    ushort_t* vtbf = kbf + (size_t)ROWS_ * 64;
    ushort_t* abf  = vtbf + (size_t)ROWS_ * 64;
    ushort_t* wob  = abf + (size_t)ROWS_ * 64;
    float*    mskf = (float*)(wob + (size_t)E_ * E_);

    // proj grid: 512 proj blocks (128 rows each) + 512 Wo-conv + 8 mask blocks
    proj_kernel<<<512 + 512 + 8, 512, 0, stream>>>(
        keys, queries, Wk, Wq, Wv, qbf, kbf, vtbf, Wo, mask, wob, mskf);
    attn_kernel<<<N_ * H_ * (L_ / 128), 512, 0, stream>>>(qbf, kbf, vtbf, mskf, abf);
    outproj_kernel<<<(N_ * L_ / 64) * (E_ / 64), 256, 0, stream>>>(abf, wob, bo, out);
}